// Round 10
// baseline (109.117 us; speedup 1.0000x reference)
//
#include <hip/hip_runtime.h>
#include <hip/hip_cooperative_groups.h>
#include <math.h>

namespace cg = cooperative_groups;

// SubGL aggregation kernel.
// out[b,l,:] = normalize(user_emb[seq[b,l]] + sum_n w[b,l,n]*user_emb[nbr[b,l,n]])
// w[b,l,n]   = dot(rel_emb[rel_neigh[b,l,n]], softmax(weight_b))
//
// Evidence (R1-R8): bytes-bound pipeline at ~6.4 TB/s; 128B line granularity;
// int8 table (1 line/row) = gather byte floor; gather restructures neutral.
// R9 cooperative fusion silently failed (launch error ignored -> zeros).
// R10: retry fusion with (a) 768 blocks (3/CU, slack vs occupancy estimate),
// (b) ERROR-CHECKED cooperative launch with same-call fallback to the proven
// two-kernel q8 path (bounds downside at 27.7us champion).

#define BB 64
#define LL 200
#define NN 32
#define DD 128
#define RR 3
#define USERS 100000

#define Q_BYTES   ((size_t)USERS * DD)           // 12.8 MB
#define SC_BYTES  ((size_t)USERS * 4)            //  0.4 MB
#define WS_NEEDED (Q_BYTES + SC_BYTES)

#define GRID_BLK  768
#define PAIRS     (BB * LL)                      // 12800

static __device__ __forceinline__ void unpack_acc(unsigned u, float ws, float4& acc)
{
    acc.x += ws * (float)((int)(signed char)(u & 0xFFu));
    acc.y += ws * (float)((int)(signed char)((u >> 8) & 0xFFu));
    acc.z += ws * (float)((int)(signed char)((u >> 16) & 0xFFu));
    acc.w += ws * (float)((int)(signed char)(u >> 24));
}

// ================= standalone quantize (two-kernel fallback) =================
__global__ __launch_bounds__(256) void quant8_kernel(
    const float* __restrict__ in,
    unsigned* __restrict__ q_tab,      // [USERS][32] packed 4x int8
    float* __restrict__ scales,
    int nrows)
{
    const int row = blockIdx.x * 8 + (threadIdx.x >> 5);
    if (row >= nrows) return;
    const int c = threadIdx.x & 31;

    const float4 v = ((const float4*)in)[(size_t)row * 32 + c];
    float m = fmaxf(fmaxf(fabsf(v.x), fabsf(v.y)), fmaxf(fabsf(v.z), fabsf(v.w)));
    #pragma unroll
    for (int k = 16; k >= 1; k >>= 1) m = fmaxf(m, __shfl_xor(m, k, 32));

    const float inv = (m > 0.0f) ? (127.0f / m) : 0.0f;
    const int q0 = (int)rintf(v.x * inv);
    const int q1 = (int)rintf(v.y * inv);
    const int q2 = (int)rintf(v.z * inv);
    const int q3 = (int)rintf(v.w * inv);

    const unsigned packed = ((unsigned)q0 & 0xFFu)
                          | (((unsigned)q1 & 0xFFu) << 8)
                          | (((unsigned)q2 & 0xFFu) << 16)
                          | (((unsigned)q3 & 0xFFu) << 24);

    q_tab[(size_t)row * 32 + c] = packed;
    if (c == 0) scales[row] = m * (1.0f / 127.0f);
}

// ================= standalone gather (two-kernel fallback, R5 champion) ======
__global__ __launch_bounds__(256) void subgl_q8_kernel(
    const int* __restrict__ sequence,
    const int* __restrict__ seq_neighbor,
    const int* __restrict__ rel_neigh,
    const unsigned* __restrict__ q_tab,
    const float* __restrict__ scales,
    const float* __restrict__ rel_emb,
    const float* __restrict__ weight_b,
    float* __restrict__ out)
{
    const int tid   = threadIdx.x;
    const int lane  = tid & 31;
    const int pair  = tid >> 5;
    const int bl    = blockIdx.x * 8 + pair;

    const float wb0 = weight_b[0], wb1 = weight_b[1], wb2 = weight_b[2];
    const float mx  = fmaxf(fmaxf(wb0, wb1), wb2);
    const float e0 = __expf(wb0 - mx), e1 = __expf(wb1 - mx), e2 = __expf(wb2 - mx);
    const float sinv = 1.0f / (e0 + e1 + e2);
    const float b0 = e0 * sinv, b1 = e1 * sinv, b2 = e2 * sinv;

    const int nbr_own = seq_neighbor[bl * NN + lane];
    const int rel_own = rel_neigh[bl * NN + lane];
    const float w_own = rel_emb[rel_own * RR + 0] * b0
                      + rel_emb[rel_own * RR + 1] * b1
                      + rel_emb[rel_own * RR + 2] * b2;
    const float ws_own = w_own * scales[nbr_own];

    const int   seq_idx = sequence[bl];
    const float s_seq   = scales[seq_idx];

    float4 acc = make_float4(0.f, 0.f, 0.f, 0.f);
    unpack_acc(q_tab[(size_t)seq_idx * 32 + lane], s_seq, acc);

    #pragma unroll 8
    for (int n = 0; n < NN; ++n) {
        const int   idx = __shfl(nbr_own, n, 32);
        const float ws  = __shfl(ws_own,  n, 32);
        unpack_acc(q_tab[(size_t)idx * 32 + lane], ws, acc);
    }

    float ss = acc.x*acc.x + acc.y*acc.y + acc.z*acc.z + acc.w*acc.w;
    #pragma unroll
    for (int k = 16; k >= 1; k >>= 1) ss += __shfl_xor(ss, k, 32);
    const float rn = 1.0f / fmaxf(sqrtf(ss), 1e-12f);

    float4 o;
    o.x = acc.x * rn; o.y = acc.y * rn; o.z = acc.z * rn; o.w = acc.w * rn;
    ((float4*)out)[(size_t)bl * (DD / 4) + lane] = o;
}

// ================= fused cooperative kernel ==================================
__global__ __launch_bounds__(256, 4) void subgl_fused_kernel(
    const int* __restrict__ sequence,
    const int* __restrict__ seq_neighbor,
    const int* __restrict__ rel_neigh,
    const float* __restrict__ user_emb,
    const float* __restrict__ rel_emb,
    const float* __restrict__ weight_b,
    unsigned* __restrict__ q_tab,
    float* __restrict__ scales,
    float* __restrict__ out)
{
    const int tid  = threadIdx.x;
    const int lane = tid & 31;
    const int grp  = tid >> 5;
    const int nblk = gridDim.x;

    // ---- Phase A: quantize (grid-stride over rows) ----
    for (int row = blockIdx.x * 8 + grp; row < USERS; row += nblk * 8) {
        const float4 v = ((const float4*)user_emb)[(size_t)row * 32 + lane];
        float m = fmaxf(fmaxf(fabsf(v.x), fabsf(v.y)), fmaxf(fabsf(v.z), fabsf(v.w)));
        #pragma unroll
        for (int k = 16; k >= 1; k >>= 1) m = fmaxf(m, __shfl_xor(m, k, 32));

        const float inv = (m > 0.0f) ? (127.0f / m) : 0.0f;
        const int q0 = (int)rintf(v.x * inv);
        const int q1 = (int)rintf(v.y * inv);
        const int q2 = (int)rintf(v.z * inv);
        const int q3 = (int)rintf(v.w * inv);

        const unsigned packed = ((unsigned)q0 & 0xFFu)
                              | (((unsigned)q1 & 0xFFu) << 8)
                              | (((unsigned)q2 & 0xFFu) << 16)
                              | (((unsigned)q3 & 0xFFu) << 24);

        q_tab[(size_t)row * 32 + lane] = packed;
        if (lane == 0) scales[row] = m * (1.0f / 127.0f);
    }

    cg::this_grid().sync();

    // ---- Phase B: gather (grid-stride over pairs) ----
    const float wb0 = weight_b[0], wb1 = weight_b[1], wb2 = weight_b[2];
    const float mx  = fmaxf(fmaxf(wb0, wb1), wb2);
    const float e0 = __expf(wb0 - mx), e1 = __expf(wb1 - mx), e2 = __expf(wb2 - mx);
    const float sinv = 1.0f / (e0 + e1 + e2);
    const float b0 = e0 * sinv, b1 = e1 * sinv, b2 = e2 * sinv;

    for (int bl = blockIdx.x * 8 + grp; bl < PAIRS; bl += nblk * 8) {
        const int nbr_own = seq_neighbor[bl * NN + lane];
        const int rel_own = rel_neigh[bl * NN + lane];
        const float w_own = rel_emb[rel_own * RR + 0] * b0
                          + rel_emb[rel_own * RR + 1] * b1
                          + rel_emb[rel_own * RR + 2] * b2;
        const float ws_own = w_own * scales[nbr_own];

        const int   seq_idx = sequence[bl];
        const float s_seq   = scales[seq_idx];

        float4 acc = make_float4(0.f, 0.f, 0.f, 0.f);
        unpack_acc(q_tab[(size_t)seq_idx * 32 + lane], s_seq, acc);

        #pragma unroll 8
        for (int n = 0; n < NN; ++n) {
            const int   idx = __shfl(nbr_own, n, 32);
            const float ws  = __shfl(ws_own,  n, 32);
            unpack_acc(q_tab[(size_t)idx * 32 + lane], ws, acc);
        }

        float ss = acc.x*acc.x + acc.y*acc.y + acc.z*acc.z + acc.w*acc.w;
        #pragma unroll
        for (int k = 16; k >= 1; k >>= 1) ss += __shfl_xor(ss, k, 32);
        const float rn = 1.0f / fmaxf(sqrtf(ss), 1e-12f);

        float4 o;
        o.x = acc.x * rn; o.y = acc.y * rn; o.z = acc.z * rn; o.w = acc.w * rn;
        ((float4*)out)[(size_t)bl * (DD / 4) + lane] = o;
    }
}

// ================= f32 direct fallback (no workspace) ========================
__global__ __launch_bounds__(256) void subgl_f32_kernel(
    const int* __restrict__ sequence,
    const int* __restrict__ seq_neighbor,
    const int* __restrict__ rel_neigh,
    const float* __restrict__ user_emb,
    const float* __restrict__ rel_emb,
    const float* __restrict__ weight_b,
    float* __restrict__ out)
{
    const int tid   = threadIdx.x;
    const int chunk = tid & 31;
    const int pair  = tid >> 5;
    const int bl    = blockIdx.x * 8 + pair;

    const float wb0 = weight_b[0], wb1 = weight_b[1], wb2 = weight_b[2];
    const float mx  = fmaxf(fmaxf(wb0, wb1), wb2);
    const float e0 = __expf(wb0 - mx), e1 = __expf(wb1 - mx), e2 = __expf(wb2 - mx);
    const float inv = 1.0f / (e0 + e1 + e2);
    const float b0 = e0 * inv, b1 = e1 * inv, b2 = e2 * inv;

    const int nbr_own = seq_neighbor[bl * NN + chunk];
    const int rel_own = rel_neigh[bl * NN + chunk];
    const float w_own = rel_emb[rel_own * RR + 0] * b0
                      + rel_emb[rel_own * RR + 1] * b1
                      + rel_emb[rel_own * RR + 2] * b2;

    const float4* __restrict__ emb4 = (const float4*)user_emb;
    const int seq_idx = sequence[bl];
    float4 acc = emb4[(size_t)seq_idx * (DD / 4) + chunk];

    #pragma unroll 4
    for (int n = 0; n < NN; ++n) {
        const int   idx = __shfl(nbr_own, n, 32);
        const float w   = __shfl(w_own,  n, 32);
        const float4 v  = emb4[(size_t)idx * (DD / 4) + chunk];
        acc.x += w * v.x; acc.y += w * v.y; acc.z += w * v.z; acc.w += w * v.w;
    }

    float ss = acc.x*acc.x + acc.y*acc.y + acc.z*acc.z + acc.w*acc.w;
    #pragma unroll
    for (int k = 16; k >= 1; k >>= 1) ss += __shfl_xor(ss, k, 32);
    const float rn = 1.0f / fmaxf(sqrtf(ss), 1e-12f);

    float4 o;
    o.x = acc.x * rn; o.y = acc.y * rn; o.z = acc.z * rn; o.w = acc.w * rn;
    ((float4*)out)[(size_t)bl * (DD / 4) + chunk] = o;
}

extern "C" void kernel_launch(void* const* d_in, const int* in_sizes, int n_in,
                              void* d_out, int out_size, void* d_ws, size_t ws_size,
                              hipStream_t stream) {
    const int*   sequence     = (const int*)d_in[0];
    const int*   seq_neighbor = (const int*)d_in[1];
    const int*   rel_neigh    = (const int*)d_in[2];
    const float* user_emb     = (const float*)d_in[3];
    const float* rel_emb      = (const float*)d_in[4];
    const float* weight_b     = (const float*)d_in[5];
    float*       out          = (float*)d_out;

    if (ws_size >= WS_NEEDED) {
        unsigned* q_tab  = (unsigned*)d_ws;
        float*    scales = (float*)((unsigned char*)d_ws + Q_BYTES);

        const int*   seq_a  = sequence;
        const int*   nbr_a  = seq_neighbor;
        const int*   rel_a  = rel_neigh;
        const float* emb_a  = user_emb;
        const float* rele_a = rel_emb;
        const float* wb_a   = weight_b;
        unsigned*    qt_a   = q_tab;
        float*       sc_a   = scales;
        float*       out_a  = out;
        void* args[] = {
            (void*)&seq_a, (void*)&nbr_a, (void*)&rel_a,
            (void*)&emb_a, (void*)&rele_a, (void*)&wb_a,
            (void*)&qt_a, (void*)&sc_a, (void*)&out_a
        };
        hipError_t err = hipLaunchCooperativeKernel(
            reinterpret_cast<void*>(subgl_fused_kernel),
            dim3(GRID_BLK), dim3(256), args, 0, stream);

        if (err != hipSuccess) {
            // deterministic fallback: proven two-kernel q8 path (27.7us)
            quant8_kernel<<<(USERS + 7) / 8, 256, 0, stream>>>(
                user_emb, q_tab, scales, USERS);
            subgl_q8_kernel<<<PAIRS / 8, 256, 0, stream>>>(
                sequence, seq_neighbor, rel_neigh, q_tab, scales,
                rel_emb, weight_b, out);
        }
    } else {
        subgl_f32_kernel<<<PAIRS / 8, 256, 0, stream>>>(
            sequence, seq_neighbor, rel_neigh, user_emb, rel_emb, weight_b, out);
    }
}

// Round 11
// 27.702 us; speedup vs baseline: 3.9390x; 3.9390x over previous
//
#include <hip/hip_runtime.h>
#include <math.h>

// SubGL aggregation kernel — CHAMPION (R8 structure, 27.7us).
// out[b,l,:] = normalize(user_emb[seq[b,l]] + sum_n w[b,l,n]*user_emb[nbr[b,l,n]])
// w[b,l,n]   = dot(rel_emb[rel_neigh[b,l,n]], softmax(weight_b))
//
// Final model (R1-R10): bytes/fabric-bound. Fetch granularity = 128B line;
// int8 per-row-scaled table (1 line/row) is the gather byte floor. Random
// 128B-line gather runs at ~3.4 TB/s (L3-resident), streaming at ~6.5 TB/s;
// floor = convert 9.9us + gather 17.5us ~= 27.4us ~= measured 27.7us.
// Ruled out: MLP staging (R7, -24%), wide 8-line loads (R8, neutral),
// split-plane 12-bit (R4, line-split loss), cooperative fusion (R10, 4x loss:
// grid.sync + occupancy cap >> launch-gap savings).

#define BB 64
#define LL 200
#define NN 32
#define DD 128
#define RR 3
#define USERS 100000

#define Q_BYTES   ((size_t)USERS * DD)           // 12.8 MB
#define SC_BYTES  ((size_t)USERS * 4)            //  0.4 MB
#define WS_NEEDED (Q_BYTES + SC_BYTES)

// ---- quantize: f32 table -> signed int8 + per-row scale. 32 lanes/row ----
__global__ __launch_bounds__(256) void quant8_kernel(
    const float* __restrict__ in,
    unsigned* __restrict__ q_tab,      // [USERS][32] packed 4x int8
    float* __restrict__ scales,
    int nrows)
{
    const int row = blockIdx.x * 8 + (threadIdx.x >> 5);
    if (row >= nrows) return;
    const int c = threadIdx.x & 31;

    const float4 v = ((const float4*)in)[(size_t)row * 32 + c];
    float m = fmaxf(fmaxf(fabsf(v.x), fabsf(v.y)), fmaxf(fabsf(v.z), fabsf(v.w)));
    #pragma unroll
    for (int k = 16; k >= 1; k >>= 1) m = fmaxf(m, __shfl_xor(m, k, 32));

    const float inv = (m > 0.0f) ? (127.0f / m) : 0.0f;
    const int q0 = (int)rintf(v.x * inv);   // [-127, 127]
    const int q1 = (int)rintf(v.y * inv);
    const int q2 = (int)rintf(v.z * inv);
    const int q3 = (int)rintf(v.w * inv);

    const unsigned packed = ((unsigned)q0 & 0xFFu)
                          | (((unsigned)q1 & 0xFFu) << 8)
                          | (((unsigned)q2 & 0xFFu) << 16)
                          | (((unsigned)q3 & 0xFFu) << 24);

    q_tab[(size_t)row * 32 + c] = packed;
    if (c == 0) scales[row] = m * (1.0f / 127.0f);
}

// unpack one dword (4 int8 dims) into acc[4j..4j+3]
static __device__ __forceinline__ void unpack4(
    unsigned u, float ws, float& a0, float& a1, float& a2, float& a3)
{
    a0 += ws * (float)((int)(signed char)(u & 0xFFu));
    a1 += ws * (float)((int)(signed char)((u >> 8) & 0xFFu));
    a2 += ws * (float)((int)(signed char)((u >> 16) & 0xFFu));
    a3 += ws * (float)((int)(signed char)(u >> 24));
}

// ---- gather: 32 lanes/pair; lane = (rslot, sub): rslot=lane>>3 picks which
// row of a 4-row batch, sub=lane&7 picks which uint4 (16 dims) of that row.
// One wave-load instruction = 64 lanes x 16B = 8 rows = 8 lines.
__global__ __launch_bounds__(256) void subgl_q8_kernel(
    const int* __restrict__ sequence,
    const int* __restrict__ seq_neighbor,
    const int* __restrict__ rel_neigh,
    const unsigned* __restrict__ q_tab,
    const float* __restrict__ scales,
    const float* __restrict__ rel_emb,
    const float* __restrict__ weight_b,
    float* __restrict__ out)
{
    const int tid   = threadIdx.x;
    const int lane  = tid & 31;
    const int pair  = tid >> 5;
    const int bl    = blockIdx.x * 8 + pair;   // 1600*8 = 12800 exact
    const int sub   = lane & 7;                // uint4 index within row
    const int rslot = lane >> 3;               // 0..3 row-slot

    // beta = softmax(weight_b)
    const float wb0 = weight_b[0], wb1 = weight_b[1], wb2 = weight_b[2];
    const float mx  = fmaxf(fmaxf(wb0, wb1), wb2);
    const float e0 = __expf(wb0 - mx), e1 = __expf(wb1 - mx), e2 = __expf(wb2 - mx);
    const float sinv = 1.0f / (e0 + e1 + e2);
    const float b0 = e0 * sinv, b1 = e1 * sinv, b2 = e2 * sinv;

    // lane n owns neighbor n's index and (w * row_scale)
    const int nbr_own = seq_neighbor[bl * NN + lane];
    const int rel_own = rel_neigh[bl * NN + lane];
    const float w_own = rel_emb[rel_own * RR + 0] * b0
                      + rel_emb[rel_own * RR + 1] * b1
                      + rel_emb[rel_own * RR + 2] * b2;
    const float ws_own = w_own * scales[nbr_own];

    const int   seq_idx = sequence[bl];
    const float s_seq   = scales[seq_idx];

    const uint4* __restrict__ q16 = (const uint4*)q_tab;  // row = 8 x uint4

    // acc[i] = partial sum for dim 16*sub + i (this lane's 16 dims),
    // covering rows n === rslot (mod 4). Folded across rslot at the end.
    float acc[16];
    #pragma unroll
    for (int i = 0; i < 16; ++i) acc[i] = 0.f;

    #pragma unroll
    for (int g = 0; g < 9; ++g) {
        int   idx;
        float ws;
        if (g < 8) {
            const int n = 4 * g + rslot;          // 0..31
            idx = __shfl(nbr_own, n, 32);
            ws  = __shfl(ws_own,  n, 32);
        } else {
            idx = seq_idx;                         // rows 32..35: seq + 3 dups
            ws  = (rslot == 0) ? s_seq : 0.0f;     // dups weighted 0 (same line)
        }
        const uint4 q = q16[(size_t)idx * 8 + sub];
        unpack4(q.x, ws, acc[0],  acc[1],  acc[2],  acc[3]);
        unpack4(q.y, ws, acc[4],  acc[5],  acc[6],  acc[7]);
        unpack4(q.z, ws, acc[8],  acc[9],  acc[10], acc[11]);
        unpack4(q.w, ws, acc[12], acc[13], acc[14], acc[15]);
    }

    // fold the 4 rslot partials (lanes differing in bits 3,4)
    #pragma unroll
    for (int i = 0; i < 16; ++i) {
        acc[i] += __shfl_xor(acc[i], 8, 32);
        acc[i] += __shfl_xor(acc[i], 16, 32);
    }

    // L2 norm: my 16 dims, then across the 8 sub-lanes (bits 0..2)
    float ss = 0.f;
    #pragma unroll
    for (int i = 0; i < 16; ++i) ss += acc[i] * acc[i];
    ss += __shfl_xor(ss, 1, 32);
    ss += __shfl_xor(ss, 2, 32);
    ss += __shfl_xor(ss, 4, 32);
    const float rn = 1.0f / fmaxf(sqrtf(ss), 1e-12f);

    // lane stores float4 #rslot of its 16 dims -> out chunk 4*sub + rslot.
    // Select with compile-time indices only (runtime acc[] index => scratch).
    float4 o;
    o.x = (rslot == 0) ? acc[0] : (rslot == 1) ? acc[4] : (rslot == 2) ? acc[8]  : acc[12];
    o.y = (rslot == 0) ? acc[1] : (rslot == 1) ? acc[5] : (rslot == 2) ? acc[9]  : acc[13];
    o.z = (rslot == 0) ? acc[2] : (rslot == 1) ? acc[6] : (rslot == 2) ? acc[10] : acc[14];
    o.w = (rslot == 0) ? acc[3] : (rslot == 1) ? acc[7] : (rslot == 2) ? acc[11] : acc[15];
    o.x *= rn; o.y *= rn; o.z *= rn; o.w *= rn;
    ((float4*)out)[(size_t)bl * 32 + 4 * sub + rslot] = o;
}

// ---- fallback: f32 gather (proven 35.5us) if workspace too small ----
__global__ __launch_bounds__(256) void subgl_f32_kernel(
    const int* __restrict__ sequence,
    const int* __restrict__ seq_neighbor,
    const int* __restrict__ rel_neigh,
    const float* __restrict__ user_emb,
    const float* __restrict__ rel_emb,
    const float* __restrict__ weight_b,
    float* __restrict__ out)
{
    const int tid   = threadIdx.x;
    const int chunk = tid & 31;
    const int pair  = tid >> 5;
    const int bl    = blockIdx.x * 8 + pair;

    const float wb0 = weight_b[0], wb1 = weight_b[1], wb2 = weight_b[2];
    const float mx  = fmaxf(fmaxf(wb0, wb1), wb2);
    const float e0 = __expf(wb0 - mx), e1 = __expf(wb1 - mx), e2 = __expf(wb2 - mx);
    const float inv = 1.0f / (e0 + e1 + e2);
    const float b0 = e0 * inv, b1 = e1 * inv, b2 = e2 * inv;

    const int nbr_own = seq_neighbor[bl * NN + chunk];
    const int rel_own = rel_neigh[bl * NN + chunk];
    const float w_own = rel_emb[rel_own * RR + 0] * b0
                      + rel_emb[rel_own * RR + 1] * b1
                      + rel_emb[rel_own * RR + 2] * b2;

    const float4* __restrict__ emb4 = (const float4*)user_emb;
    const int seq_idx = sequence[bl];
    float4 acc = emb4[(size_t)seq_idx * (DD / 4) + chunk];

    #pragma unroll 4
    for (int n = 0; n < NN; ++n) {
        const int   idx = __shfl(nbr_own, n, 32);
        const float w   = __shfl(w_own,  n, 32);
        const float4 v  = emb4[(size_t)idx * (DD / 4) + chunk];
        acc.x += w * v.x; acc.y += w * v.y; acc.z += w * v.z; acc.w += w * v.w;
    }

    float ss = acc.x*acc.x + acc.y*acc.y + acc.z*acc.z + acc.w*acc.w;
    #pragma unroll
    for (int k = 16; k >= 1; k >>= 1) ss += __shfl_xor(ss, k, 32);
    const float rn = 1.0f / fmaxf(sqrtf(ss), 1e-12f);

    float4 o;
    o.x = acc.x * rn; o.y = acc.y * rn; o.z = acc.z * rn; o.w = acc.w * rn;
    ((float4*)out)[(size_t)bl * (DD / 4) + chunk] = o;
}

extern "C" void kernel_launch(void* const* d_in, const int* in_sizes, int n_in,
                              void* d_out, int out_size, void* d_ws, size_t ws_size,
                              hipStream_t stream) {
    const int*   sequence     = (const int*)d_in[0];
    const int*   seq_neighbor = (const int*)d_in[1];
    const int*   rel_neigh    = (const int*)d_in[2];
    const float* user_emb     = (const float*)d_in[3];
    const float* rel_emb      = (const float*)d_in[4];
    const float* weight_b     = (const float*)d_in[5];
    float*       out          = (float*)d_out;

    const int grid = (BB * LL) / 8;   // 1600 blocks

    if (ws_size >= WS_NEEDED) {
        unsigned* q_tab  = (unsigned*)d_ws;
        float*    scales = (float*)((unsigned char*)d_ws + Q_BYTES);

        quant8_kernel<<<(USERS + 7) / 8, 256, 0, stream>>>(
            user_emb, q_tab, scales, USERS);
        subgl_q8_kernel<<<grid, 256, 0, stream>>>(
            sequence, seq_neighbor, rel_neigh, q_tab, scales,
            rel_emb, weight_b, out);
    } else {
        subgl_f32_kernel<<<grid, 256, 0, stream>>>(
            sequence, seq_neighbor, rel_neigh, user_emb, rel_emb, weight_b, out);
    }
}